// Round 3
// baseline (279.536 us; speedup 1.0000x reference)
//
#include <hip/hip_runtime.h>

#define C_IN 128
#define C_OUT 64
#define BN_EPS 1e-5f
#define LEAKY 0.01f

#define BSZ   256   // nodes per bucket (bucket = col >> 8)
#define NBMAX 512   // max buckets (n <= 131072)
#define CAP   6144  // pairs capacity per bucket (mean 4096, sigma ~64 -> safe)
#define CHUNKA 2048 // edges per binA block

using bf16x8 = __attribute__((ext_vector_type(8))) __bf16;
using f32x4  = __attribute__((ext_vector_type(4))) float;

// bf16 pack/unpack (RNE pack; unpack is exact shift)
__device__ inline unsigned short f2b(float f) {
    unsigned u = __float_as_uint(f);
    return (unsigned short)((u + 0x7fffu + ((u >> 16) & 1u)) >> 16);
}
__device__ inline float b2f(unsigned short b) {
    return __uint_as_float(((unsigned)b) << 16);
}

// ---------------------------------------------------------------------------
// k_prep: fuses (1) W repack to per-lane MFMA B-fragment order, (2) bfill
// zeroing, (3) stats zeroing. Replaces 2 memsets + k_wprep -> 1 launch.
// wb[(((t*4+c)*4+q)*16 + nlo)*8 + j] = bf16(W[(c*32+q*8+j)*64 + t*16+nlo])
__global__ __launch_bounds__(256) void k_prep(const float* __restrict__ W,
                                              unsigned short* __restrict__ wb,
                                              int* __restrict__ bfill,
                                              float* __restrict__ stats) {
    int idx = blockIdx.x * 256 + threadIdx.x;   // grid covers 8192
    if (idx < NBMAX) bfill[idx] = 0;
    if (idx >= NBMAX && idx < NBMAX + 2 * C_OUT) stats[idx - NBMAX] = 0.f;
    if (idx >= C_IN * C_OUT) return;
    int k = idx >> 6, col = idx & 63;
    int t = col >> 4, nlo = col & 15;
    int c = k >> 5, q = (k >> 3) & 3, j = k & 7;
    wb[(size_t)((((t * 4 + c) * 4 + q) * 16) + nlo) * 8 + j] = f2b(W[idx]);
}

// ---------------------------------------------------------------------------
// binA: bin edges by destination bucket. Per block: LDS histogram of its
// chunk, ONE global atomic per touched bucket to reserve space, then write
// packed 4 B pairs ((col&255)<<24 | row) into the bucket's fixed-CAP region.
__global__ __launch_bounds__(256) void k_binA(const int* __restrict__ rows,
                                              const int* __restrict__ cols,
                                              int* __restrict__ bfill,
                                              unsigned* __restrict__ pairs,
                                              int nE, int NB) {
    __shared__ int hist[NBMAX];
    __shared__ int base[NBMAX];
    int t = threadIdx.x;
    int chunk = blockIdx.x * CHUNKA;
    int e = min(chunk + CHUNKA, nE);

    for (int b = t; b < NB; b += 256) hist[b] = 0;
    __syncthreads();

    for (int i = chunk + t; i < e; i += 256)
        atomicAdd(&hist[cols[i] >> 8], 1);
    __syncthreads();

    for (int b = t; b < NB; b += 256) {
        int cnt = hist[b];
        base[b] = cnt ? atomicAdd(&bfill[b], cnt) : 0;
        hist[b] = 0;  // becomes local cursor
    }
    __syncthreads();

    for (int i = chunk + t; i < e; i += 256) {
        int c = cols[i];
        unsigned r = (unsigned)rows[i];
        int b = c >> 8;
        int off = base[b] + atomicAdd(&hist[b], 1);
        if (off < CAP)  // defensive; never hit
            pairs[(size_t)b * CAP + off] = ((unsigned)(c & (BSZ - 1)) << 24) | r;
    }
}

// ---------------------------------------------------------------------------
// binB: one block per bucket, sorts its pairs region IN PLACE (stages all of
// it in LDS before the first write -> srcs aliases pairs, no scan kernel:
// srcs base for bucket b is simply b*CAP). Emits pd[node] = (csr_start, deg).
__global__ __launch_bounds__(256) void k_binB(const int* __restrict__ bfill,
                                              const unsigned* __restrict__ pairs,
                                              int2* __restrict__ pd,
                                              int* __restrict__ srcs, int n) {
    __shared__ unsigned rowbuf[CAP];
    __shared__ int sorted[CAP];
    __shared__ int histL[BSZ];
    __shared__ int scanL[BSZ];
    int b = blockIdx.x;
    int t = threadIdx.x;
    int cnt = min(bfill[b], CAP);
    const unsigned* reg = pairs + (size_t)b * CAP;

    histL[t] = 0;
    __syncthreads();
    for (int i = t; i < cnt; i += 256) {
        unsigned p = reg[i];          // all reads of the region happen here,
        rowbuf[i] = p;                // before any write below (in-place safe)
        atomicAdd(&histL[p >> 24], 1);
    }
    __syncthreads();

    int hv = histL[t];
    scanL[t] = hv;
    __syncthreads();
    for (int off = 1; off < 256; off <<= 1) {
        int x = (t >= off) ? scanL[t - off] : 0;
        __syncthreads();
        scanL[t] += x;
        __syncthreads();
    }
    int my_start = scanL[t] - hv;  // exclusive within bucket

    int s0 = b * CAP;              // fixed per-bucket region: no global scan
    int node = (b << 8) + t;
    if (node < n) pd[node] = make_int2(s0 + my_start, hv);
    __syncthreads();
    histL[t] = my_start;  // cursor
    __syncthreads();
    for (int i = t; i < cnt; i += 256) {
        unsigned p = rowbuf[i];
        int pos = atomicAdd(&histL[p >> 24], 1);
        sorted[pos] = (int)(p & 0xFFFFFFu);
    }
    __syncthreads();
    for (int i = t; i < cnt; i += 256)
        srcs[s0 + i] = sorted[i];
}

// ---------------------------------------------------------------------------
// K3: xwsb = bf16( (x @ W) * rsqrt(deg+1) ) via MFMA 16x16x32 bf16, NO LDS.
// One wave = 16 nodes x 64 channels. B-frags vector-loaded from wb (L2-hot).
// Layouts (m89-verified): A[m=lane&15][k=quad*8+j], B[k=quad*8+j][n=lane&15],
// D: col=lane&15, row=quad*4+reg.
__global__ __launch_bounds__(256) void k_gemm(const float* __restrict__ x,
                                              const unsigned short* __restrict__ wb,
                                              const int2* __restrict__ pd,
                                              unsigned short* __restrict__ xwsb, int n) {
    const int lane = threadIdx.x & 63;
    const int wave = threadIdx.x >> 6;
    const int base = (blockIdx.x * 4 + wave) * 16;
    if (base >= n) return;

    const int nlo  = lane & 15;
    const int quad = lane >> 4;

    const bf16x8* Wv = (const bf16x8*)wb;
    bf16x8 Bf[4][4];
    #pragma unroll
    for (int t = 0; t < 4; ++t)
        #pragma unroll
        for (int c = 0; c < 4; ++c)
            Bf[t][c] = Wv[((t * 4 + c) * 4 + quad) * 16 + nlo];

    f32x4 acc[4] = {};
    int m = base + nlo;
    const float* xrow = x + (size_t)(m < n ? m : n - 1) * C_IN;

    #pragma unroll
    for (int c = 0; c < 4; ++c) {
        float4 a0 = *(const float4*)&xrow[c * 32 + quad * 8];
        float4 a1 = *(const float4*)&xrow[c * 32 + quad * 8 + 4];
        bf16x8 Af;
        Af[0] = (__bf16)a0.x; Af[1] = (__bf16)a0.y;
        Af[2] = (__bf16)a0.z; Af[3] = (__bf16)a0.w;
        Af[4] = (__bf16)a1.x; Af[5] = (__bf16)a1.y;
        Af[6] = (__bf16)a1.z; Af[7] = (__bf16)a1.w;
        #pragma unroll
        for (int t = 0; t < 4; ++t)
            acc[t] = __builtin_amdgcn_mfma_f32_16x16x32_bf16(Af, Bf[t][c], acc[t], 0, 0, 0);
    }

    #pragma unroll
    for (int r = 0; r < 4; ++r) {
        int node = base + quad * 4 + r;
        if (node < n) {
            float dn = rsqrtf((float)(pd[node].y + 1));
            #pragma unroll
            for (int t = 0; t < 4; ++t)
                xwsb[(size_t)node * C_OUT + t * 16 + nlo] = f2b(acc[t][r] * dn);
        }
    }
}

// ---------------------------------------------------------------------------
// K6: gather-aggregate + fused BN-stats. Persistent grid-stride blocks, one
// wave per node per iteration. lane=(g,s): g=lane>>3 picks 1 of 8 sources
// per step, s=lane&7 picks a 16B slice (8 bf16 ch) of the 128B row.
// Inner j-loop is STATICALLY unrolled 8x with per-lane guards (R2 regression
// lesson: a dynamic bound kills the unroll -> loads serialize on vmcnt(0);
// the unrolled form keeps ~8 gathers in flight, empty groups skip via execz).
// Depth-2 pipeline: pd prefetched 2 iters ahead so the srcs/self prefetch
// 1 iter ahead never waits on its own pd load.
// Epilogue per node: 7-shuffle reduce-scatter -> lane owns channel c; store
// + per-lane sum/sumsq; block-end LDS reduce + 128 atomics (fused k_stats).
#define ACC8(d) do { \
    acc[0] += __uint_as_float((d).x << 16); \
    acc[1] += __uint_as_float((d).x & 0xffff0000u); \
    acc[2] += __uint_as_float((d).y << 16); \
    acc[3] += __uint_as_float((d).y & 0xffff0000u); \
    acc[4] += __uint_as_float((d).z << 16); \
    acc[5] += __uint_as_float((d).z & 0xffff0000u); \
    acc[6] += __uint_as_float((d).w << 16); \
    acc[7] += __uint_as_float((d).w & 0xffff0000u); } while (0)

__global__ __launch_bounds__(256) void k_gather(const int2* __restrict__ pd,
                                                const int* __restrict__ srcs,
                                                const unsigned short* __restrict__ xwsb,
                                                float* __restrict__ out,
                                                float* __restrict__ stats, int n) {
    int lane = threadIdx.x & 63;
    int wv = threadIdx.x >> 6;
    int s = lane & 7;
    int g = lane >> 3;
    int c = s * 8 + ((lane & 8) ? 4 : 0) + ((lane & 16) ? 2 : 0) + ((lane & 32) ? 1 : 0);
    const uint4* xw16 = (const uint4*)xwsb;  // 1 uint4 = 8 bf16; row = 8 uint4
    int stride = gridDim.x * 4;

    float ssum = 0.f, ssq = 0.f;

    int node = blockIdx.x * 4 + wv;
    int2 p0 = (node < n) ? pd[node] : make_int2(0, 0);
    int sv0 = (node < n && lane < p0.y) ? srcs[p0.x + lane] : 0;
    float self0 = (node < n) ? b2f(xwsb[(size_t)node * C_OUT + c]) : 0.f;
    int2 p1 = (node + stride < n) ? pd[node + stride] : make_int2(0, 0);

    while (node < n) {
        // prefetch: pd two ahead; srcs/self one ahead (p1 already resident)
        int2 p2 = (node + 2 * stride < n) ? pd[node + 2 * stride] : make_int2(0, 0);
        int sv1 = 0;
        float self1 = 0.f;
        if (node + stride < n) {
            sv1 = (lane < p1.y) ? srcs[p1.x + lane] : 0;
            self1 = b2f(xwsb[(size_t)(node + stride) * C_OUT + c]);
        }

        int dg = p0.y;
        float dn = rsqrtf((float)(dg + 1));
        float acc[8] = {0.f, 0.f, 0.f, 0.f, 0.f, 0.f, 0.f, 0.f};

        int svb = sv0;
        for (int b2 = 0;;) {
            int m = dg - b2;  // lanes/groups beyond m masked by guards below
            #pragma unroll
            for (int j = 0; j < 8; ++j) {
                int idx = j * 8 + g;
                int src = __shfl(svb, idx);
                if (idx < m) {
                    uint4 d = xw16[((size_t)src << 3) + s];
                    ACC8(d);
                }
            }
            b2 += 64;
            if (b2 >= dg) break;  // deg>64 ~never (Poisson mean 16)
            int mm = dg - b2;
            svb = (lane < mm) ? srcs[p0.x + b2 + lane] : 0;
        }

        // reduce-scatter across the 8 g-groups: 4+2+1 exchanges
        #pragma unroll
        for (int k = 0; k < 4; ++k) {
            float send = (lane & 8) ? acc[k] : acc[k + 4];
            float recv = __shfl_xor(send, 8);
            acc[k] = ((lane & 8) ? acc[k + 4] : acc[k]) + recv;
        }
        #pragma unroll
        for (int k = 0; k < 2; ++k) {
            float send = (lane & 16) ? acc[k] : acc[k + 2];
            float recv = __shfl_xor(send, 16);
            acc[k] = ((lane & 16) ? acc[k + 2] : acc[k]) + recv;
        }
        {
            float send = (lane & 32) ? acc[0] : acc[1];
            float recv = __shfl_xor(send, 32);
            acc[0] = ((lane & 32) ? acc[1] : acc[0]) + recv;
        }

        float v = (acc[0] + self0) * dn;
        out[(size_t)node * C_OUT + c] = v;
        ssum += v;
        ssq += v * v;

        node += stride;
        p0 = p1; p1 = p2; sv0 = sv1; self0 = self1;
    }

    // fused BN stats: per-wave lanes map bijectively onto channels 0..63
    __shared__ float red[2][4][64];
    red[0][wv][c] = ssum;
    red[1][wv][c] = ssq;
    __syncthreads();
    if (wv == 0) {
        float a = red[0][0][c] + red[0][1][c] + red[0][2][c] + red[0][3][c];
        float q = red[1][0][c] + red[1][1][c] + red[1][2][c] + red[1][3][c];
        atomicAdd(&stats[c], a);
        atomicAdd(&stats[C_OUT + c], q);
    }
}

// ---------------------------------------------------------------------------
// K8: BN normalize + LeakyReLU, float4, in-place. (GCN bias b cancels in BN.)
__global__ __launch_bounds__(256) void k_final(const float* __restrict__ stats,
                                               const float* __restrict__ gamma,
                                               const float* __restrict__ beta,
                                               float* __restrict__ out, int n) {
    int gid = blockIdx.x * 256 + threadIdx.x;
    int total4 = n * (C_OUT / 4);
    if (gid >= total4) return;
    int c4 = (gid & 15) * 4;
    float inv_n = 1.0f / (float)n;
    float4 s  = *(const float4*)&stats[c4];
    float4 s2 = *(const float4*)&stats[64 + c4];
    float4 g4 = *(const float4*)&gamma[c4];
    float4 b4 = *(const float4*)&beta[c4];
    float4 v = ((const float4*)out)[gid];

    float m, var, k, y;
    m = s.x * inv_n; var = s2.x * inv_n - m * m; k = rsqrtf(var + BN_EPS) * g4.x;
    y = (v.x - m) * k + b4.x; v.x = y >= 0.f ? y : LEAKY * y;
    m = s.y * inv_n; var = s2.y * inv_n - m * m; k = rsqrtf(var + BN_EPS) * g4.y;
    y = (v.y - m) * k + b4.y; v.y = y >= 0.f ? y : LEAKY * y;
    m = s.z * inv_n; var = s2.z * inv_n - m * m; k = rsqrtf(var + BN_EPS) * g4.z;
    y = (v.z - m) * k + b4.z; v.z = y >= 0.f ? y : LEAKY * y;
    m = s.w * inv_n; var = s2.w * inv_n - m * m; k = rsqrtf(var + BN_EPS) * g4.w;
    y = (v.w - m) * k + b4.w; v.w = y >= 0.f ? y : LEAKY * y;

    ((float4*)out)[gid] = v;
}

// ---------------------------------------------------------------------------
extern "C" void kernel_launch(void* const* d_in, const int* in_sizes, int n_in,
                              void* d_out, int out_size, void* d_ws, size_t ws_size,
                              hipStream_t stream) {
    const float* x     = (const float*)d_in[0];
    const int*   ei    = (const int*)d_in[1];
    const float* W     = (const float*)d_in[2];
    // d_in[3] = b: cancels in BatchNorm, unused.
    const float* gamma = (const float*)d_in[4];
    const float* beta  = (const float*)d_in[5];
    float* out = (float*)d_out;

    int n  = in_sizes[0] / C_IN;
    int nE = in_sizes[1] / 2;
    const int* rows = ei;
    const int* cols = ei + nE;
    int NB = (n + BSZ - 1) / BSZ;  // 391 for n=100k (<= NBMAX)

    // ws layout (srcs ALIASES pairs: binB sorts in place):
    // pd[n] int2 | xwsb[n*64] ushort | pairs/srcs[NB*CAP] | bfill[NBMAX] |
    // stats[128] f32 | wb[8192] ushort        (~23.3 MB total)
    int2* pd = (int2*)d_ws;
    unsigned short* xwsb = (unsigned short*)(pd + n);
    unsigned* pairs = (unsigned*)(xwsb + (size_t)n * C_OUT);
    int* srcs = (int*)pairs;
    int* bfill = (int*)(pairs + (size_t)NB * CAP);
    float* stats = (float*)(bfill + NBMAX);
    unsigned short* wb = (unsigned short*)(stats + 2 * C_OUT);

    // 6 graph nodes: prep, binA, binB, gemm, gather, final
    k_prep<<<(C_IN * C_OUT + 255) / 256, 256, 0, stream>>>(W, wb, bfill, stats);
    k_binA<<<(nE + CHUNKA - 1) / CHUNKA, 256, 0, stream>>>(rows, cols, bfill, pairs, nE, NB);
    k_binB<<<NB, 256, 0, stream>>>(bfill, pairs, pd, srcs, n);
    k_gemm<<<(n + 63) / 64, 256, 0, stream>>>(x, wb, pd, xwsb, n);
    k_gather<<<4096, 256, 0, stream>>>(pd, srcs, xwsb, out, stats, n);
    k_final<<<(n * (C_OUT / 4) + 255) / 256, 256, 0, stream>>>(stats, gamma, beta, out, n);
}

// Round 4
// 221.902 us; speedup vs baseline: 1.2597x; 1.2597x over previous
//
#include <hip/hip_runtime.h>

#define C_IN 128
#define C_OUT 64
#define BN_EPS 1e-5f
#define LEAKY 0.01f

#define BSZ   256   // nodes per bucket (bucket = col >> 8)
#define NBMAX 512   // max buckets (n <= 131072)
#define CAP   6144  // pairs capacity per bucket (mean 4096, sigma ~64 -> safe)
#define CHUNKA 2048 // edges per binA block

using bf16x8 = __attribute__((ext_vector_type(8))) __bf16;
using f32x4  = __attribute__((ext_vector_type(4))) float;

// bf16 pack/unpack (RNE pack; unpack is exact shift)
__device__ inline unsigned short f2b(float f) {
    unsigned u = __float_as_uint(f);
    return (unsigned short)((u + 0x7fffu + ((u >> 16) & 1u)) >> 16);
}
__device__ inline float b2f(unsigned short b) {
    return __uint_as_float(((unsigned)b) << 16);
}

// ---------------------------------------------------------------------------
// k_prep: fuses (1) W repack to per-lane MFMA B-fragment order, (2) bfill
// zeroing, (3) stats zeroing. Replaces 2 memsets + k_wprep -> 1 launch.
// wb[(((t*4+c)*4+q)*16 + nlo)*8 + j] = bf16(W[(c*32+q*8+j)*64 + t*16+nlo])
__global__ __launch_bounds__(256) void k_prep(const float* __restrict__ W,
                                              unsigned short* __restrict__ wb,
                                              int* __restrict__ bfill,
                                              float* __restrict__ stats) {
    int idx = blockIdx.x * 256 + threadIdx.x;   // grid covers 8192
    if (idx < NBMAX) bfill[idx] = 0;
    if (idx >= NBMAX && idx < NBMAX + 2 * C_OUT) stats[idx - NBMAX] = 0.f;
    if (idx >= C_IN * C_OUT) return;
    int k = idx >> 6, col = idx & 63;
    int t = col >> 4, nlo = col & 15;
    int c = k >> 5, q = (k >> 3) & 3, j = k & 7;
    wb[(size_t)((((t * 4 + c) * 4 + q) * 16) + nlo) * 8 + j] = f2b(W[idx]);
}

// ---------------------------------------------------------------------------
// binA: bin edges by destination bucket. Per block: LDS histogram of its
// chunk, ONE global atomic per touched bucket to reserve space, then write
// packed 4 B pairs ((col&255)<<24 | row) into the bucket's fixed-CAP region.
__global__ __launch_bounds__(256) void k_binA(const int* __restrict__ rows,
                                              const int* __restrict__ cols,
                                              int* __restrict__ bfill,
                                              unsigned* __restrict__ pairs,
                                              int nE, int NB) {
    __shared__ int hist[NBMAX];
    __shared__ int base[NBMAX];
    int t = threadIdx.x;
    int chunk = blockIdx.x * CHUNKA;
    int e = min(chunk + CHUNKA, nE);

    for (int b = t; b < NB; b += 256) hist[b] = 0;
    __syncthreads();

    for (int i = chunk + t; i < e; i += 256)
        atomicAdd(&hist[cols[i] >> 8], 1);
    __syncthreads();

    for (int b = t; b < NB; b += 256) {
        int cnt = hist[b];
        base[b] = cnt ? atomicAdd(&bfill[b], cnt) : 0;
        hist[b] = 0;  // becomes local cursor
    }
    __syncthreads();

    for (int i = chunk + t; i < e; i += 256) {
        int c = cols[i];
        unsigned r = (unsigned)rows[i];
        int b = c >> 8;
        int off = base[b] + atomicAdd(&hist[b], 1);
        if (off < CAP)  // defensive; never hit
            pairs[(size_t)b * CAP + off] = ((unsigned)(c & (BSZ - 1)) << 24) | r;
    }
}

// ---------------------------------------------------------------------------
// binB: one block per bucket, sorts its pairs region IN PLACE (stages all of
// it in LDS before the first write -> srcs aliases pairs, no scan kernel:
// srcs base for bucket b is simply b*CAP). Emits pd[node] = (csr_start, deg).
__global__ __launch_bounds__(256) void k_binB(const int* __restrict__ bfill,
                                              const unsigned* __restrict__ pairs,
                                              int2* __restrict__ pd,
                                              int* __restrict__ srcs, int n) {
    __shared__ unsigned rowbuf[CAP];
    __shared__ int sorted[CAP];
    __shared__ int histL[BSZ];
    __shared__ int scanL[BSZ];
    int b = blockIdx.x;
    int t = threadIdx.x;
    int cnt = min(bfill[b], CAP);
    const unsigned* reg = pairs + (size_t)b * CAP;

    histL[t] = 0;
    __syncthreads();
    for (int i = t; i < cnt; i += 256) {
        unsigned p = reg[i];          // all reads of the region happen here,
        rowbuf[i] = p;                // before any write below (in-place safe)
        atomicAdd(&histL[p >> 24], 1);
    }
    __syncthreads();

    int hv = histL[t];
    scanL[t] = hv;
    __syncthreads();
    for (int off = 1; off < 256; off <<= 1) {
        int x = (t >= off) ? scanL[t - off] : 0;
        __syncthreads();
        scanL[t] += x;
        __syncthreads();
    }
    int my_start = scanL[t] - hv;  // exclusive within bucket

    int s0 = b * CAP;              // fixed per-bucket region: no global scan
    int node = (b << 8) + t;
    if (node < n) pd[node] = make_int2(s0 + my_start, hv);
    __syncthreads();
    histL[t] = my_start;  // cursor
    __syncthreads();
    for (int i = t; i < cnt; i += 256) {
        unsigned p = rowbuf[i];
        int pos = atomicAdd(&histL[p >> 24], 1);
        sorted[pos] = (int)(p & 0xFFFFFFu);
    }
    __syncthreads();
    for (int i = t; i < cnt; i += 256)
        srcs[s0 + i] = sorted[i];
}

// ---------------------------------------------------------------------------
// K3: xwsb = bf16( (x @ W) * rsqrt(deg+1) ) via MFMA 16x16x32 bf16, NO LDS.
// One wave = 16 nodes x 64 channels. B-frags vector-loaded from wb (L2-hot).
// Layouts (m89-verified): A[m=lane&15][k=quad*8+j], B[k=quad*8+j][n=lane&15],
// D: col=lane&15, row=quad*4+reg.
__global__ __launch_bounds__(256) void k_gemm(const float* __restrict__ x,
                                              const unsigned short* __restrict__ wb,
                                              const int2* __restrict__ pd,
                                              unsigned short* __restrict__ xwsb, int n) {
    const int lane = threadIdx.x & 63;
    const int wave = threadIdx.x >> 6;
    const int base = (blockIdx.x * 4 + wave) * 16;
    if (base >= n) return;

    const int nlo  = lane & 15;
    const int quad = lane >> 4;

    const bf16x8* Wv = (const bf16x8*)wb;
    bf16x8 Bf[4][4];
    #pragma unroll
    for (int t = 0; t < 4; ++t)
        #pragma unroll
        for (int c = 0; c < 4; ++c)
            Bf[t][c] = Wv[((t * 4 + c) * 4 + quad) * 16 + nlo];

    f32x4 acc[4] = {};
    int m = base + nlo;
    const float* xrow = x + (size_t)(m < n ? m : n - 1) * C_IN;

    #pragma unroll
    for (int c = 0; c < 4; ++c) {
        float4 a0 = *(const float4*)&xrow[c * 32 + quad * 8];
        float4 a1 = *(const float4*)&xrow[c * 32 + quad * 8 + 4];
        bf16x8 Af;
        Af[0] = (__bf16)a0.x; Af[1] = (__bf16)a0.y;
        Af[2] = (__bf16)a0.z; Af[3] = (__bf16)a0.w;
        Af[4] = (__bf16)a1.x; Af[5] = (__bf16)a1.y;
        Af[6] = (__bf16)a1.z; Af[7] = (__bf16)a1.w;
        #pragma unroll
        for (int t = 0; t < 4; ++t)
            acc[t] = __builtin_amdgcn_mfma_f32_16x16x32_bf16(Af, Bf[t][c], acc[t], 0, 0, 0);
    }

    #pragma unroll
    for (int r = 0; r < 4; ++r) {
        int node = base + quad * 4 + r;
        if (node < n) {
            float dn = rsqrtf((float)(pd[node].y + 1));
            #pragma unroll
            for (int t = 0; t < 4; ++t)
                xwsb[(size_t)node * C_OUT + t * 16 + nlo] = f2b(acc[t][r] * dn);
        }
    }
}

// ---------------------------------------------------------------------------
// K6: gather-aggregate, TWO nodes per wave (one per 32-lane half).
// Non-persistent, no prefetch chains (R2/R3 lesson: loop-carried prefetch
// registers serialize vmcnt and killed MLP; R1's short-lived-wave form is
// the verified-fast structure). lane=(h,g,s): h=lane>>5 selects the node,
// g=(lane>>3)&3 selects 1-of-4 sources per step, s=lane&7 a 16B row slice.
// Inner j-loop statically unrolled 8x with per-lane guards (keeps ~8 gather
// loads in flight). Epilogue: 2-stage reduce-scatter within the half ->
// each lane owns a contiguous channel PAIR -> float2 store (coalesced 256B
// per node). Each wave retires 2 nodes per latency chain (vs 1 in R1).
#define ACC8(d) do { \
    acc[0] += __uint_as_float((d).x << 16); \
    acc[1] += __uint_as_float((d).x & 0xffff0000u); \
    acc[2] += __uint_as_float((d).y << 16); \
    acc[3] += __uint_as_float((d).y & 0xffff0000u); \
    acc[4] += __uint_as_float((d).z << 16); \
    acc[5] += __uint_as_float((d).z & 0xffff0000u); \
    acc[6] += __uint_as_float((d).w << 16); \
    acc[7] += __uint_as_float((d).w & 0xffff0000u); } while (0)

__global__ __launch_bounds__(256) void k_gather(const int2* __restrict__ pd,
                                                const int* __restrict__ srcs,
                                                const unsigned short* __restrict__ xwsb,
                                                float* __restrict__ out, int n) {
    int lane = threadIdx.x & 63;
    int wv   = threadIdx.x >> 6;
    int s    = lane & 7;
    int g    = (lane >> 3) & 3;
    int h    = lane >> 5;
    int l32  = lane & 31;
    // channel pair owned after reduce-scatter: c0 = s*8 + gbit0*4 + gbit1*2
    int c0 = s * 8 + ((lane & 8) ? 4 : 0) + ((lane & 16) ? 2 : 0);
    const uint4* xw16 = (const uint4*)xwsb;  // 1 uint4 = 8 bf16; row = 8 uint4

    int node = blockIdx.x * 8 + wv * 2 + h;
    bool active = node < n;

    int2 p = active ? pd[node] : make_int2(0, 0);
    int dg = p.y;
    float dn = rsqrtf((float)(dg + 1));
    // self-loop term: 2 bf16 channels (c0, c0+1) as one aligned dword
    unsigned selfu = active ? *(const unsigned*)&xwsb[(size_t)node * C_OUT + c0] : 0u;

    float acc[8] = {0.f, 0.f, 0.f, 0.f, 0.f, 0.f, 0.f, 0.f};

    int sv = (active && l32 < dg) ? srcs[p.x + l32] : 0;
    for (int b2 = 0;;) {
        int m = dg - b2;   // groups beyond m masked by the idx<m guard
        #pragma unroll
        for (int j = 0; j < 8; ++j) {
            int idx = j * 4 + g;
            int src = __shfl(sv, (h << 5) + idx);  // stays within own half
            if (idx < m) {
                uint4 d = xw16[((size_t)src << 3) + s];
                ACC8(d);
            }
        }
        b2 += 32;
        if (b2 >= dg) break;  // deg>32: ~15 nodes total (Poisson mean 16)
        sv = (l32 < dg - b2) ? srcs[p.x + b2 + l32] : 0;
    }

    // reduce-scatter across the 4 g-groups (within the 32-lane half): 2 stages
    #pragma unroll
    for (int k = 0; k < 4; ++k) {
        float send = (lane & 8) ? acc[k] : acc[k + 4];
        float recv = __shfl_xor(send, 8);
        acc[k] = ((lane & 8) ? acc[k + 4] : acc[k]) + recv;
    }
    #pragma unroll
    for (int k = 0; k < 2; ++k) {
        float send = (lane & 16) ? acc[k] : acc[k + 2];
        float recv = __shfl_xor(send, 16);
        acc[k] = ((lane & 16) ? acc[k + 2] : acc[k]) + recv;
    }

    if (active) {
        float v0 = (acc[0] + __uint_as_float(selfu << 16)) * dn;
        float v1 = (acc[1] + __uint_as_float(selfu & 0xffff0000u)) * dn;
        *(float2*)&out[(size_t)node * C_OUT + c0] = make_float2(v0, v1);
    }
}

// ---------------------------------------------------------------------------
// K7: per-channel sum and sumsq. stats[0..63]=sum, stats[64..127]=sumsq.
__global__ __launch_bounds__(256) void k_stats(const float* __restrict__ agg,
                                               float* __restrict__ stats, int n) {
    int c = threadIdx.x & 63;
    int sub = threadIdx.x >> 6;
    float s = 0.f, s2 = 0.f;
    for (int node = blockIdx.x * 4 + sub; node < n; node += gridDim.x * 4) {
        float v = agg[(size_t)node * C_OUT + c];
        s += v;
        s2 += v * v;
    }
    __shared__ float red[2][4][64];
    red[0][sub][c] = s;
    red[1][sub][c] = s2;
    __syncthreads();
    if (sub == 0) {
        s  = red[0][0][c] + red[0][1][c] + red[0][2][c] + red[0][3][c];
        s2 = red[1][0][c] + red[1][1][c] + red[1][2][c] + red[1][3][c];
        atomicAdd(&stats[c], s);
        atomicAdd(&stats[64 + c], s2);
    }
}

// ---------------------------------------------------------------------------
// K8: BN normalize + LeakyReLU, float4, in-place. (GCN bias b cancels in BN.)
__global__ __launch_bounds__(256) void k_final(const float* __restrict__ stats,
                                               const float* __restrict__ gamma,
                                               const float* __restrict__ beta,
                                               float* __restrict__ out, int n) {
    int gid = blockIdx.x * 256 + threadIdx.x;
    int total4 = n * (C_OUT / 4);
    if (gid >= total4) return;
    int c4 = (gid & 15) * 4;
    float inv_n = 1.0f / (float)n;
    float4 s  = *(const float4*)&stats[c4];
    float4 s2 = *(const float4*)&stats[64 + c4];
    float4 g4 = *(const float4*)&gamma[c4];
    float4 b4 = *(const float4*)&beta[c4];
    float4 v = ((const float4*)out)[gid];

    float m, var, k, y;
    m = s.x * inv_n; var = s2.x * inv_n - m * m; k = rsqrtf(var + BN_EPS) * g4.x;
    y = (v.x - m) * k + b4.x; v.x = y >= 0.f ? y : LEAKY * y;
    m = s.y * inv_n; var = s2.y * inv_n - m * m; k = rsqrtf(var + BN_EPS) * g4.y;
    y = (v.y - m) * k + b4.y; v.y = y >= 0.f ? y : LEAKY * y;
    m = s.z * inv_n; var = s2.z * inv_n - m * m; k = rsqrtf(var + BN_EPS) * g4.z;
    y = (v.z - m) * k + b4.z; v.z = y >= 0.f ? y : LEAKY * y;
    m = s.w * inv_n; var = s2.w * inv_n - m * m; k = rsqrtf(var + BN_EPS) * g4.w;
    y = (v.w - m) * k + b4.w; v.w = y >= 0.f ? y : LEAKY * y;

    ((float4*)out)[gid] = v;
}

// ---------------------------------------------------------------------------
extern "C" void kernel_launch(void* const* d_in, const int* in_sizes, int n_in,
                              void* d_out, int out_size, void* d_ws, size_t ws_size,
                              hipStream_t stream) {
    const float* x     = (const float*)d_in[0];
    const int*   ei    = (const int*)d_in[1];
    const float* W     = (const float*)d_in[2];
    // d_in[3] = b: cancels in BatchNorm, unused.
    const float* gamma = (const float*)d_in[4];
    const float* beta  = (const float*)d_in[5];
    float* out = (float*)d_out;

    int n  = in_sizes[0] / C_IN;
    int nE = in_sizes[1] / 2;
    const int* rows = ei;
    const int* cols = ei + nE;
    int NB = (n + BSZ - 1) / BSZ;  // 391 for n=100k (<= NBMAX)

    // ws layout (srcs ALIASES pairs: binB sorts in place):
    // pd[n] int2 | xwsb[n*64] ushort | pairs/srcs[NB*CAP] | bfill[NBMAX] |
    // stats[128] f32 | wb[8192] ushort        (~23.3 MB total)
    int2* pd = (int2*)d_ws;
    unsigned short* xwsb = (unsigned short*)(pd + n);
    unsigned* pairs = (unsigned*)(xwsb + (size_t)n * C_OUT);
    int* srcs = (int*)pairs;
    int* bfill = (int*)(pairs + (size_t)NB * CAP);
    float* stats = (float*)(bfill + NBMAX);
    unsigned short* wb = (unsigned short*)(stats + 2 * C_OUT);

    // 7 graph nodes: prep, binA, binB, gemm, gather, stats, final
    k_prep<<<(C_IN * C_OUT + 255) / 256, 256, 0, stream>>>(W, wb, bfill, stats);
    k_binA<<<(nE + CHUNKA - 1) / CHUNKA, 256, 0, stream>>>(rows, cols, bfill, pairs, nE, NB);
    k_binB<<<NB, 256, 0, stream>>>(bfill, pairs, pd, srcs, n);
    k_gemm<<<(n + 63) / 64, 256, 0, stream>>>(x, wb, pd, xwsb, n);
    k_gather<<<(n + 7) / 8, 256, 0, stream>>>(pd, srcs, xwsb, out, n);
    k_stats<<<512, 256, 0, stream>>>(out, stats, n);
    k_final<<<(n * (C_OUT / 4) + 255) / 256, 256, 0, stream>>>(stats, gamma, beta, out, n);
}

// Round 6
// 216.635 us; speedup vs baseline: 1.2904x; 1.0243x over previous
//
#include <hip/hip_runtime.h>

#define C_IN 128
#define C_OUT 64
#define BN_EPS 1e-5f
#define LEAKY 0.01f

#define BSZ   256   // nodes per bucket (bucket = col >> 8)
#define NBMAX 512   // max buckets (n <= 131072)
#define CAP   6144  // pairs capacity per bucket (mean 4096, sigma ~64 -> safe)
#define CHUNKA 2048 // edges per binA block

using bf16x8 = __attribute__((ext_vector_type(8))) __bf16;
using f32x4  = __attribute__((ext_vector_type(4))) float;

// bf16 pack/unpack (RNE pack; unpack is exact shift)
__device__ inline unsigned short f2b(float f) {
    unsigned u = __float_as_uint(f);
    return (unsigned short)((u + 0x7fffu + ((u >> 16) & 1u)) >> 16);
}
__device__ inline float b2f(unsigned short b) {
    return __uint_as_float(((unsigned)b) << 16);
}

// ---------------------------------------------------------------------------
// k_prep: fuses (1) W repack to per-lane MFMA B-fragment order, (2) bfill
// zeroing, (3) stats zeroing. Replaces 2 memsets + k_wprep -> 1 launch.
// wb[(((t*4+c)*4+q)*16 + nlo)*8 + j] = bf16(W[(c*32+q*8+j)*64 + t*16+nlo])
__global__ __launch_bounds__(256) void k_prep(const float* __restrict__ W,
                                              unsigned short* __restrict__ wb,
                                              int* __restrict__ bfill,
                                              float* __restrict__ stats) {
    int idx = blockIdx.x * 256 + threadIdx.x;   // grid covers 8192
    if (idx < NBMAX) bfill[idx] = 0;
    if (idx >= NBMAX && idx < NBMAX + 2 * C_OUT) stats[idx - NBMAX] = 0.f;
    if (idx >= C_IN * C_OUT) return;
    int k = idx >> 6, col = idx & 63;
    int t = col >> 4, nlo = col & 15;
    int c = k >> 5, q = (k >> 3) & 3, j = k & 7;
    wb[(size_t)((((t * 4 + c) * 4 + q) * 16) + nlo) * 8 + j] = f2b(W[idx]);
}

// ---------------------------------------------------------------------------
// binA: bin edges by destination bucket WITH in-LDS chunk sort (R4 lesson:
// the per-edge random 4B global scatter was 64-way address-divergent -> each
// wave store = ~64 transactions, kernel transaction-bound at 1.7% VALU).
// Now: stage packed pairs + bucket in LDS during histogram, reserve global
// space per bucket, LDS scan + reorder into bucket-sorted order, then write
// out sorted: consecutive threads hit consecutive addresses within each
// bucket run (avg 5.2 edges) -> ~5x fewer write transactions.
__global__ __launch_bounds__(256) void k_binA(const int* __restrict__ rows,
                                              const int* __restrict__ cols,
                                              int* __restrict__ bfill,
                                              unsigned* __restrict__ pairs,
                                              int nE, int NB) {
    __shared__ int hist[NBMAX];
    __shared__ int base[NBMAX];    // global reserved base per bucket
    __shared__ int lstart[NBMAX];  // local (in-chunk) exclusive start
    __shared__ int cursor[NBMAX];
    __shared__ unsigned lpair[CHUNKA];
    __shared__ unsigned short lbkt[CHUNKA];
    __shared__ unsigned lsorted[CHUNKA];
    __shared__ unsigned short lsbkt[CHUNKA];
    int t = threadIdx.x;
    int chunk = blockIdx.x * CHUNKA;
    int cnt = min(chunk + CHUNKA, nE) - chunk;

    hist[t] = 0; hist[t + 256] = 0;
    __syncthreads();

    // phase 1: load once, stage packed pair + bucket, LDS histogram
    for (int i = t; i < cnt; i += 256) {
        int c = cols[chunk + i];
        unsigned r = (unsigned)rows[chunk + i];
        int b = c >> 8;
        lpair[i] = ((unsigned)(c & (BSZ - 1)) << 24) | r;
        lbkt[i] = (unsigned short)b;
        atomicAdd(&hist[b], 1);
    }
    __syncthreads();

    // phase 2: global reserve; seed local scan
    int h0 = hist[t], h1 = hist[t + 256];
    if (t < NB && h0) base[t] = atomicAdd(&bfill[t], h0);
    if (t + 256 < NB && h1) base[t + 256] = atomicAdd(&bfill[t + 256], h1);
    lstart[t] = h0; lstart[t + 256] = h1;
    __syncthreads();
    // phase 3: Hillis-Steele inclusive scan over 512 entries (2 per thread)
    for (int off = 1; off < 512; off <<= 1) {
        int a = (t >= off) ? lstart[t - off] : 0;
        int bb = lstart[t + 256 - off];   // t+256-off >= 0 always (off<=256)
        __syncthreads();
        lstart[t] += a; lstart[t + 256] += bb;
        __syncthreads();
    }
    int s0 = lstart[t] - h0, s1 = lstart[t + 256] - h1;  // own-entry only
    lstart[t] = s0; lstart[t + 256] = s1;                // inclusive->exclusive
    cursor[t] = s0; cursor[t + 256] = s1;
    __syncthreads();

    // phase 4: reorder into bucket-sorted LDS order
    for (int i = t; i < cnt; i += 256) {
        int b = lbkt[i];
        int pos = atomicAdd(&cursor[b], 1);
        lsorted[pos] = lpair[i];
        lsbkt[pos] = (unsigned short)b;
    }
    __syncthreads();

    // phase 5: write out sorted -> consecutive addrs within each bucket run
    for (int i = t; i < cnt; i += 256) {
        int b = lsbkt[i];
        int off = base[b] + (i - lstart[b]);
        if (off < CAP)  // defensive; never hit
            pairs[(size_t)b * CAP + off] = lsorted[i];
    }
}

// ---------------------------------------------------------------------------
// binB: one block per bucket, sorts its pairs region IN PLACE (stages all of
// it in LDS before the first write -> srcs aliases pairs, no scan kernel:
// srcs base for bucket b is simply b*CAP). Emits pd[node] = (csr_start, deg).
__global__ __launch_bounds__(256) void k_binB(const int* __restrict__ bfill,
                                              const unsigned* __restrict__ pairs,
                                              int2* __restrict__ pd,
                                              int* __restrict__ srcs, int n) {
    __shared__ unsigned rowbuf[CAP];
    __shared__ int sorted[CAP];
    __shared__ int histL[BSZ];
    __shared__ int scanL[BSZ];
    int b = blockIdx.x;
    int t = threadIdx.x;
    int cnt = min(bfill[b], CAP);
    const unsigned* reg = pairs + (size_t)b * CAP;

    histL[t] = 0;
    __syncthreads();
    for (int i = t; i < cnt; i += 256) {
        unsigned p = reg[i];          // all reads of the region happen here,
        rowbuf[i] = p;                // before any write below (in-place safe)
        atomicAdd(&histL[p >> 24], 1);
    }
    __syncthreads();

    int hv = histL[t];
    scanL[t] = hv;
    __syncthreads();
    for (int off = 1; off < 256; off <<= 1) {
        int x = (t >= off) ? scanL[t - off] : 0;
        __syncthreads();
        scanL[t] += x;
        __syncthreads();
    }
    int my_start = scanL[t] - hv;  // exclusive within bucket

    int s0 = b * CAP;              // fixed per-bucket region: no global scan
    int node = (b << 8) + t;
    if (node < n) pd[node] = make_int2(s0 + my_start, hv);
    __syncthreads();
    histL[t] = my_start;  // cursor
    __syncthreads();
    for (int i = t; i < cnt; i += 256) {
        unsigned p = rowbuf[i];
        int pos = atomicAdd(&histL[p >> 24], 1);
        sorted[pos] = (int)(p & 0xFFFFFFu);
    }
    __syncthreads();
    for (int i = t; i < cnt; i += 256)
        srcs[s0 + i] = sorted[i];
}

// ---------------------------------------------------------------------------
// K3: xwsb = bf16( (x @ W) * rsqrt(deg+1) ) via MFMA 16x16x32 bf16, NO LDS.
// One wave = 16 nodes x 64 channels. B-frags vector-loaded from wb (L2-hot).
// Layouts (m89-verified): A[m=lane&15][k=quad*8+j], B[k=quad*8+j][n=lane&15],
// D: col=lane&15, row=quad*4+reg.
__global__ __launch_bounds__(256) void k_gemm(const float* __restrict__ x,
                                              const unsigned short* __restrict__ wb,
                                              const int2* __restrict__ pd,
                                              unsigned short* __restrict__ xwsb, int n) {
    const int lane = threadIdx.x & 63;
    const int wave = threadIdx.x >> 6;
    const int base = (blockIdx.x * 4 + wave) * 16;
    if (base >= n) return;

    const int nlo  = lane & 15;
    const int quad = lane >> 4;

    const bf16x8* Wv = (const bf16x8*)wb;
    bf16x8 Bf[4][4];
    #pragma unroll
    for (int t = 0; t < 4; ++t)
        #pragma unroll
        for (int c = 0; c < 4; ++c)
            Bf[t][c] = Wv[((t * 4 + c) * 4 + quad) * 16 + nlo];

    f32x4 acc[4] = {};
    int m = base + nlo;
    const float* xrow = x + (size_t)(m < n ? m : n - 1) * C_IN;

    #pragma unroll
    for (int c = 0; c < 4; ++c) {
        float4 a0 = *(const float4*)&xrow[c * 32 + quad * 8];
        float4 a1 = *(const float4*)&xrow[c * 32 + quad * 8 + 4];
        bf16x8 Af;
        Af[0] = (__bf16)a0.x; Af[1] = (__bf16)a0.y;
        Af[2] = (__bf16)a0.z; Af[3] = (__bf16)a0.w;
        Af[4] = (__bf16)a1.x; Af[5] = (__bf16)a1.y;
        Af[6] = (__bf16)a1.z; Af[7] = (__bf16)a1.w;
        #pragma unroll
        for (int t = 0; t < 4; ++t)
            acc[t] = __builtin_amdgcn_mfma_f32_16x16x32_bf16(Af, Bf[t][c], acc[t], 0, 0, 0);
    }

    #pragma unroll
    for (int r = 0; r < 4; ++r) {
        int node = base + quad * 4 + r;
        if (node < n) {
            float dn = rsqrtf((float)(pd[node].y + 1));
            #pragma unroll
            for (int t = 0; t < 4; ++t)
                xwsb[(size_t)node * C_OUT + t * 16 + nlo] = f2b(acc[t][r] * dn);
        }
    }
}

// ---------------------------------------------------------------------------
// K6: gather-aggregate, TWO nodes per wave (one per 32-lane half).
// Non-persistent, no prefetch chains (R2/R3 lesson: loop-carried prefetch
// registers serialize vmcnt and killed MLP; R1's short-lived-wave form is
// the verified-fast structure). lane=(h,g,s): h=lane>>5 selects the node,
// g=(lane>>3)&3 selects 1-of-4 sources per step, s=lane&7 a 16B row slice.
// Inner j-loop statically unrolled 8x with per-lane guards (keeps ~8 gather
// loads in flight). Epilogue: 2-stage reduce-scatter within the half ->
// each lane owns a contiguous channel PAIR -> float2 store (coalesced 256B
// per node). Each wave retires 2 nodes per latency chain (vs 1 in R1).
#define ACC8(d) do { \
    acc[0] += __uint_as_float((d).x << 16); \
    acc[1] += __uint_as_float((d).x & 0xffff0000u); \
    acc[2] += __uint_as_float((d).y << 16); \
    acc[3] += __uint_as_float((d).y & 0xffff0000u); \
    acc[4] += __uint_as_float((d).z << 16); \
    acc[5] += __uint_as_float((d).z & 0xffff0000u); \
    acc[6] += __uint_as_float((d).w << 16); \
    acc[7] += __uint_as_float((d).w & 0xffff0000u); } while (0)

__global__ __launch_bounds__(256) void k_gather(const int2* __restrict__ pd,
                                                const int* __restrict__ srcs,
                                                const unsigned short* __restrict__ xwsb,
                                                float* __restrict__ out, int n) {
    int lane = threadIdx.x & 63;
    int wv   = threadIdx.x >> 6;
    int s    = lane & 7;
    int g    = (lane >> 3) & 3;
    int h    = lane >> 5;
    int l32  = lane & 31;
    // channel pair owned after reduce-scatter: c0 = s*8 + gbit0*4 + gbit1*2
    int c0 = s * 8 + ((lane & 8) ? 4 : 0) + ((lane & 16) ? 2 : 0);
    const uint4* xw16 = (const uint4*)xwsb;  // 1 uint4 = 8 bf16; row = 8 uint4

    int node = blockIdx.x * 8 + wv * 2 + h;
    bool active = node < n;

    int2 p = active ? pd[node] : make_int2(0, 0);
    int dg = p.y;
    float dn = rsqrtf((float)(dg + 1));
    // self-loop term: 2 bf16 channels (c0, c0+1) as one aligned dword
    unsigned selfu = active ? *(const unsigned*)&xwsb[(size_t)node * C_OUT + c0] : 0u;

    float acc[8] = {0.f, 0.f, 0.f, 0.f, 0.f, 0.f, 0.f, 0.f};

    int sv = (active && l32 < dg) ? srcs[p.x + l32] : 0;
    for (int b2 = 0;;) {
        int m = dg - b2;   // groups beyond m masked by the idx<m guard
        #pragma unroll
        for (int j = 0; j < 8; ++j) {
            int idx = j * 4 + g;
            int src = __shfl(sv, (h << 5) + idx);  // stays within own half
            if (idx < m) {
                uint4 d = xw16[((size_t)src << 3) + s];
                ACC8(d);
            }
        }
        b2 += 32;
        if (b2 >= dg) break;  // deg>32: ~15 nodes total (Poisson mean 16)
        sv = (l32 < dg - b2) ? srcs[p.x + b2 + l32] : 0;
    }

    // reduce-scatter across the 4 g-groups (within the 32-lane half): 2 stages
    #pragma unroll
    for (int k = 0; k < 4; ++k) {
        float send = (lane & 8) ? acc[k] : acc[k + 4];
        float recv = __shfl_xor(send, 8);
        acc[k] = ((lane & 8) ? acc[k + 4] : acc[k]) + recv;
    }
    #pragma unroll
    for (int k = 0; k < 2; ++k) {
        float send = (lane & 16) ? acc[k] : acc[k + 2];
        float recv = __shfl_xor(send, 16);
        acc[k] = ((lane & 16) ? acc[k + 2] : acc[k]) + recv;
    }

    if (active) {
        float v0 = (acc[0] + __uint_as_float(selfu << 16)) * dn;
        float v1 = (acc[1] + __uint_as_float(selfu & 0xffff0000u)) * dn;
        *(float2*)&out[(size_t)node * C_OUT + c0] = make_float2(v0, v1);
    }
}

// ---------------------------------------------------------------------------
// K7: per-channel sum and sumsq. stats[0..63]=sum, stats[64..127]=sumsq.
__global__ __launch_bounds__(256) void k_stats(const float* __restrict__ agg,
                                               float* __restrict__ stats, int n) {
    int c = threadIdx.x & 63;
    int sub = threadIdx.x >> 6;
    float s = 0.f, s2 = 0.f;
    for (int node = blockIdx.x * 4 + sub; node < n; node += gridDim.x * 4) {
        float v = agg[(size_t)node * C_OUT + c];
        s += v;
        s2 += v * v;
    }
    __shared__ float red[2][4][64];
    red[0][sub][c] = s;
    red[1][sub][c] = s2;
    __syncthreads();
    if (sub == 0) {
        s  = red[0][0][c] + red[0][1][c] + red[0][2][c] + red[0][3][c];
        s2 = red[1][0][c] + red[1][1][c] + red[1][2][c] + red[1][3][c];
        atomicAdd(&stats[c], s);
        atomicAdd(&stats[64 + c], s2);
    }
}

// ---------------------------------------------------------------------------
// K8: BN normalize + LeakyReLU, float4, in-place. (GCN bias b cancels in BN.)
__global__ __launch_bounds__(256) void k_final(const float* __restrict__ stats,
                                               const float* __restrict__ gamma,
                                               const float* __restrict__ beta,
                                               float* __restrict__ out, int n) {
    int gid = blockIdx.x * 256 + threadIdx.x;
    int total4 = n * (C_OUT / 4);
    if (gid >= total4) return;
    int c4 = (gid & 15) * 4;
    float inv_n = 1.0f / (float)n;
    float4 s  = *(const float4*)&stats[c4];
    float4 s2 = *(const float4*)&stats[64 + c4];
    float4 g4 = *(const float4*)&gamma[c4];
    float4 b4 = *(const float4*)&beta[c4];
    float4 v = ((const float4*)out)[gid];

    float m, var, k, y;
    m = s.x * inv_n; var = s2.x * inv_n - m * m; k = rsqrtf(var + BN_EPS) * g4.x;
    y = (v.x - m) * k + b4.x; v.x = y >= 0.f ? y : LEAKY * y;
    m = s.y * inv_n; var = s2.y * inv_n - m * m; k = rsqrtf(var + BN_EPS) * g4.y;
    y = (v.y - m) * k + b4.y; v.y = y >= 0.f ? y : LEAKY * y;
    m = s.z * inv_n; var = s2.z * inv_n - m * m; k = rsqrtf(var + BN_EPS) * g4.z;
    y = (v.z - m) * k + b4.z; v.z = y >= 0.f ? y : LEAKY * y;
    m = s.w * inv_n; var = s2.w * inv_n - m * m; k = rsqrtf(var + BN_EPS) * g4.w;
    y = (v.w - m) * k + b4.w; v.w = y >= 0.f ? y : LEAKY * y;

    ((float4*)out)[gid] = v;
}

// ---------------------------------------------------------------------------
extern "C" void kernel_launch(void* const* d_in, const int* in_sizes, int n_in,
                              void* d_out, int out_size, void* d_ws, size_t ws_size,
                              hipStream_t stream) {
    const float* x     = (const float*)d_in[0];
    const int*   ei    = (const int*)d_in[1];
    const float* W     = (const float*)d_in[2];
    // d_in[3] = b: cancels in BatchNorm, unused.
    const float* gamma = (const float*)d_in[4];
    const float* beta  = (const float*)d_in[5];
    float* out = (float*)d_out;

    int n  = in_sizes[0] / C_IN;
    int nE = in_sizes[1] / 2;
    const int* rows = ei;
    const int* cols = ei + nE;
    int NB = (n + BSZ - 1) / BSZ;  // 391 for n=100k (<= NBMAX)

    // ws layout (srcs ALIASES pairs: binB sorts in place):
    // pd[n] int2 | xwsb[n*64] ushort | pairs/srcs[NB*CAP] | bfill[NBMAX] |
    // stats[128] f32 | wb[8192] ushort        (~23.3 MB total)
    int2* pd = (int2*)d_ws;
    unsigned short* xwsb = (unsigned short*)(pd + n);
    unsigned* pairs = (unsigned*)(xwsb + (size_t)n * C_OUT);
    int* srcs = (int*)pairs;
    int* bfill = (int*)(pairs + (size_t)NB * CAP);
    float* stats = (float*)(bfill + NBMAX);
    unsigned short* wb = (unsigned short*)(stats + 2 * C_OUT);

    // 7 graph nodes: prep, binA, binB, gemm, gather, stats, final
    k_prep<<<(C_IN * C_OUT + 255) / 256, 256, 0, stream>>>(W, wb, bfill, stats);
    k_binA<<<(nE + CHUNKA - 1) / CHUNKA, 256, 0, stream>>>(rows, cols, bfill, pairs, nE, NB);
    k_binB<<<NB, 256, 0, stream>>>(bfill, pairs, pd, srcs, n);
    k_gemm<<<(n + 63) / 64, 256, 0, stream>>>(x, wb, pd, xwsb, n);
    k_gather<<<(n + 7) / 8, 256, 0, stream>>>(pd, srcs, xwsb, out, n);
    k_stats<<<512, 256, 0, stream>>>(out, stats, n);
    k_final<<<(n * (C_OUT / 4) + 255) / 256, 256, 0, stream>>>(stats, gamma, beta, out, n);
}

// Round 7
// 197.004 us; speedup vs baseline: 1.4189x; 1.0996x over previous
//
#include <hip/hip_runtime.h>

#define C_IN 128
#define C_OUT 64
#define BN_EPS 1e-5f
#define LEAKY 0.01f

#define BSZ   256   // nodes per bucket (bucket = col >> 8)
#define NBMAX 512   // max buckets (n <= 131072)
#define CAP   6144  // pairs capacity per bucket (mean 4096, sigma ~64 -> safe)
#define CHUNKA 2048 // edges per binA block
#define NPART 16    // stats partial buffers (contention /16)

using bf16x8 = __attribute__((ext_vector_type(8))) __bf16;
using f32x4  = __attribute__((ext_vector_type(4))) float;

// bf16 pack/unpack (RNE pack; unpack is exact shift)
__device__ inline unsigned short f2b(float f) {
    unsigned u = __float_as_uint(f);
    return (unsigned short)((u + 0x7fffu + ((u >> 16) & 1u)) >> 16);
}
__device__ inline float b2f(unsigned short b) {
    return __uint_as_float(((unsigned)b) << 16);
}

// ---------------------------------------------------------------------------
// k_prep: fuses (1) W repack to per-lane MFMA B-fragment order, (2) bfill
// zeroing, (3) stats-partials zeroing. One launch replaces 2 memsets+wprep.
// wb[(((t*4+c)*4+q)*16 + nlo)*8 + j] = bf16(W[(c*32+q*8+j)*64 + t*16+nlo])
__global__ __launch_bounds__(256) void k_prep(const float* __restrict__ W,
                                              unsigned short* __restrict__ wb,
                                              int* __restrict__ bfill,
                                              float* __restrict__ part) {
    int idx = blockIdx.x * 256 + threadIdx.x;   // grid covers 8192
    if (idx < NBMAX) bfill[idx] = 0;
    if (idx < NPART * 128) part[idx] = 0.f;
    if (idx >= C_IN * C_OUT) return;
    int k = idx >> 6, col = idx & 63;
    int t = col >> 4, nlo = col & 15;
    int c = k >> 5, q = (k >> 3) & 3, j = k & 7;
    wb[(size_t)((((t * 4 + c) * 4 + q) * 16) + nlo) * 8 + j] = f2b(W[idx]);
}

// ---------------------------------------------------------------------------
// binA: bin edges by destination bucket WITH in-LDS chunk sort (R4 lesson:
// per-edge random 4B global scatter was 64-way address-divergent). Stage
// packed pairs + bucket in LDS during histogram, reserve global space per
// bucket, LDS scan + reorder into bucket-sorted order, write sorted runs.
__global__ __launch_bounds__(256) void k_binA(const int* __restrict__ rows,
                                              const int* __restrict__ cols,
                                              int* __restrict__ bfill,
                                              unsigned* __restrict__ pairs,
                                              int nE, int NB) {
    __shared__ int hist[NBMAX];
    __shared__ int base[NBMAX];    // global reserved base per bucket
    __shared__ int lstart[NBMAX];  // local (in-chunk) exclusive start
    __shared__ int cursor[NBMAX];
    __shared__ unsigned lpair[CHUNKA];
    __shared__ unsigned short lbkt[CHUNKA];
    __shared__ unsigned lsorted[CHUNKA];
    __shared__ unsigned short lsbkt[CHUNKA];
    int t = threadIdx.x;
    int chunk = blockIdx.x * CHUNKA;
    int cnt = min(chunk + CHUNKA, nE) - chunk;

    hist[t] = 0; hist[t + 256] = 0;
    __syncthreads();

    // phase 1: load once, stage packed pair + bucket, LDS histogram
    for (int i = t; i < cnt; i += 256) {
        int c = cols[chunk + i];
        unsigned r = (unsigned)rows[chunk + i];
        int b = c >> 8;
        lpair[i] = ((unsigned)(c & (BSZ - 1)) << 24) | r;
        lbkt[i] = (unsigned short)b;
        atomicAdd(&hist[b], 1);
    }
    __syncthreads();

    // phase 2: global reserve; seed local scan
    int h0 = hist[t], h1 = hist[t + 256];
    if (t < NB && h0) base[t] = atomicAdd(&bfill[t], h0);
    if (t + 256 < NB && h1) base[t + 256] = atomicAdd(&bfill[t + 256], h1);
    lstart[t] = h0; lstart[t + 256] = h1;
    __syncthreads();
    // phase 3: Hillis-Steele inclusive scan over 512 entries (2 per thread)
    for (int off = 1; off < 512; off <<= 1) {
        int a = (t >= off) ? lstart[t - off] : 0;
        int bb = lstart[t + 256 - off];   // t+256-off >= 0 always (off<=256)
        __syncthreads();
        lstart[t] += a; lstart[t + 256] += bb;
        __syncthreads();
    }
    int s0 = lstart[t] - h0, s1 = lstart[t + 256] - h1;  // own-entry only
    lstart[t] = s0; lstart[t + 256] = s1;                // inclusive->exclusive
    cursor[t] = s0; cursor[t + 256] = s1;
    __syncthreads();

    // phase 4: reorder into bucket-sorted LDS order
    for (int i = t; i < cnt; i += 256) {
        int b = lbkt[i];
        int pos = atomicAdd(&cursor[b], 1);
        lsorted[pos] = lpair[i];
        lsbkt[pos] = (unsigned short)b;
    }
    __syncthreads();

    // phase 5: write out sorted -> consecutive addrs within each bucket run
    for (int i = t; i < cnt; i += 256) {
        int b = lsbkt[i];
        int off = base[b] + (i - lstart[b]);
        if (off < CAP)  // defensive; never hit
            pairs[(size_t)b * CAP + off] = lsorted[i];
    }
}

// ---------------------------------------------------------------------------
// binB: one block per bucket, sorts its pairs region IN PLACE (stages all of
// it in LDS before the first write -> srcs aliases pairs, no scan kernel:
// srcs base for bucket b is simply b*CAP). Emits pd[node] = (csr_start, deg).
__global__ __launch_bounds__(256) void k_binB(const int* __restrict__ bfill,
                                              const unsigned* __restrict__ pairs,
                                              int2* __restrict__ pd,
                                              int* __restrict__ srcs, int n) {
    __shared__ unsigned rowbuf[CAP];
    __shared__ int sorted[CAP];
    __shared__ int histL[BSZ];
    __shared__ int scanL[BSZ];
    int b = blockIdx.x;
    int t = threadIdx.x;
    int cnt = min(bfill[b], CAP);
    const unsigned* reg = pairs + (size_t)b * CAP;

    histL[t] = 0;
    __syncthreads();
    for (int i = t; i < cnt; i += 256) {
        unsigned p = reg[i];          // all reads of the region happen here,
        rowbuf[i] = p;                // before any write below (in-place safe)
        atomicAdd(&histL[p >> 24], 1);
    }
    __syncthreads();

    int hv = histL[t];
    scanL[t] = hv;
    __syncthreads();
    for (int off = 1; off < 256; off <<= 1) {
        int x = (t >= off) ? scanL[t - off] : 0;
        __syncthreads();
        scanL[t] += x;
        __syncthreads();
    }
    int my_start = scanL[t] - hv;  // exclusive within bucket

    int s0 = b * CAP;              // fixed per-bucket region: no global scan
    int node = (b << 8) + t;
    if (node < n) pd[node] = make_int2(s0 + my_start, hv);
    __syncthreads();
    histL[t] = my_start;  // cursor
    __syncthreads();
    for (int i = t; i < cnt; i += 256) {
        unsigned p = rowbuf[i];
        int pos = atomicAdd(&histL[p >> 24], 1);
        sorted[pos] = (int)(p & 0xFFFFFFu);
    }
    __syncthreads();
    for (int i = t; i < cnt; i += 256)
        srcs[s0 + i] = sorted[i];
}

// ---------------------------------------------------------------------------
// K3: xwsb = bf16( (x @ W) * rsqrt(deg+1) ) via MFMA 16x16x32 bf16, NO LDS.
// One wave = 16 nodes x 64 channels. B-frags vector-loaded from wb (L2-hot).
// Layouts (m89-verified): A[m=lane&15][k=quad*8+j], B[k=quad*8+j][n=lane&15],
// D: col=lane&15, row=quad*4+reg.
__global__ __launch_bounds__(256) void k_gemm(const float* __restrict__ x,
                                              const unsigned short* __restrict__ wb,
                                              const int2* __restrict__ pd,
                                              unsigned short* __restrict__ xwsb, int n) {
    const int lane = threadIdx.x & 63;
    const int wave = threadIdx.x >> 6;
    const int base = (blockIdx.x * 4 + wave) * 16;
    if (base >= n) return;

    const int nlo  = lane & 15;
    const int quad = lane >> 4;

    const bf16x8* Wv = (const bf16x8*)wb;
    bf16x8 Bf[4][4];
    #pragma unroll
    for (int t = 0; t < 4; ++t)
        #pragma unroll
        for (int c = 0; c < 4; ++c)
            Bf[t][c] = Wv[((t * 4 + c) * 4 + quad) * 16 + nlo];

    f32x4 acc[4] = {};
    int m = base + nlo;
    const float* xrow = x + (size_t)(m < n ? m : n - 1) * C_IN;

    #pragma unroll
    for (int c = 0; c < 4; ++c) {
        float4 a0 = *(const float4*)&xrow[c * 32 + quad * 8];
        float4 a1 = *(const float4*)&xrow[c * 32 + quad * 8 + 4];
        bf16x8 Af;
        Af[0] = (__bf16)a0.x; Af[1] = (__bf16)a0.y;
        Af[2] = (__bf16)a0.z; Af[3] = (__bf16)a0.w;
        Af[4] = (__bf16)a1.x; Af[5] = (__bf16)a1.y;
        Af[6] = (__bf16)a1.z; Af[7] = (__bf16)a1.w;
        #pragma unroll
        for (int t = 0; t < 4; ++t)
            acc[t] = __builtin_amdgcn_mfma_f32_16x16x32_bf16(Af, Bf[t][c], acc[t], 0, 0, 0);
    }

    #pragma unroll
    for (int r = 0; r < 4; ++r) {
        int node = base + quad * 4 + r;
        if (node < n) {
            float dn = rsqrtf((float)(pd[node].y + 1));
            #pragma unroll
            for (int t = 0; t < 4; ++t)
                xwsb[(size_t)node * C_OUT + t * 16 + nlo] = f2b(acc[t][r] * dn);
        }
    }
}

// ---------------------------------------------------------------------------
// K6: gather-aggregate, FOUR nodes per wave (one per 16-lane quarter) +
// fused BN-stats. Non-persistent, no prefetch chains (R2/R3 lesson).
// lane=(q,g,s): q=lane>>4 selects the node, g=(lane>>3)&1 selects 1-of-2
// sources per step, s=lane&7 a 16B slice (8 bf16 ch) of the 128B row.
// Inner j-loop statically unrolled 8x with per-lane guards (8-deep MLP,
// R2 lesson: dynamic bound kills it). Epilogue: ONE exchange stage ->
// lane owns 4 consecutive channels -> float4 store (coalesced 256B/node).
// Each wave retires 4 nodes per latency chain (vs 2 in R4, 2x validated).
// BN stats: non-atomic LDS slots (unique slot,channel writer), 1 barrier,
// 128 fire-and-forget atomics/block into 16-way partials (~390/addr).
#define ACC8(d) do { \
    acc[0] += __uint_as_float((d).x << 16); \
    acc[1] += __uint_as_float((d).x & 0xffff0000u); \
    acc[2] += __uint_as_float((d).y << 16); \
    acc[3] += __uint_as_float((d).y & 0xffff0000u); \
    acc[4] += __uint_as_float((d).z << 16); \
    acc[5] += __uint_as_float((d).z & 0xffff0000u); \
    acc[6] += __uint_as_float((d).w << 16); \
    acc[7] += __uint_as_float((d).w & 0xffff0000u); } while (0)

__global__ __launch_bounds__(256) void k_gather(const int2* __restrict__ pd,
                                                const int* __restrict__ srcs,
                                                const unsigned short* __restrict__ xwsb,
                                                float* __restrict__ out,
                                                float* __restrict__ part, int n) {
    __shared__ float sredS[16][64];
    __shared__ float sredQ[16][64];
    int lane = threadIdx.x & 63;
    int wv   = threadIdx.x >> 6;
    int s    = lane & 7;
    int g    = (lane >> 3) & 1;
    int q    = lane >> 4;
    int l16  = lane & 15;
    // 4 consecutive channels owned after exchange: c0 = s*8 + (gbit ? 4 : 0)
    int c0 = s * 8 + ((lane & 8) ? 4 : 0);
    const uint4* xw16 = (const uint4*)xwsb;  // 1 uint4 = 8 bf16; row = 8 uint4

    int node = blockIdx.x * 16 + wv * 4 + q;
    bool active = node < n;

    int2 p = active ? pd[node] : make_int2(0, 0);
    int dg = p.y;
    float dn = rsqrtf((float)(dg + 1));
    // self-loop term: 4 bf16 channels (c0..c0+3) as one aligned uint2
    uint2 selfu = active ? *(const uint2*)&xwsb[(size_t)node * C_OUT + c0]
                         : make_uint2(0u, 0u);

    float acc[8] = {0.f, 0.f, 0.f, 0.f, 0.f, 0.f, 0.f, 0.f};

    int sv = (active && l16 < dg) ? srcs[p.x + l16] : 0;
    for (int b2 = 0;;) {
        int m = dg - b2;   // groups beyond m masked by the idx<m guard
        #pragma unroll
        for (int j = 0; j < 8; ++j) {
            int idx = j * 2 + g;
            int src = __shfl(sv, (lane & 48) + idx);  // stays within quarter
            if (idx < m) {
                uint4 d = xw16[((size_t)src << 3) + s];
                ACC8(d);
            }
        }
        b2 += 16;
        if (b2 >= dg) break;
        sv = (l16 < dg - b2) ? srcs[p.x + b2 + l16] : 0;
    }

    // one exchange stage across the 2 g-groups (partner = lane^8)
    #pragma unroll
    for (int k = 0; k < 4; ++k) {
        float send = (lane & 8) ? acc[k] : acc[k + 4];
        float recv = __shfl_xor(send, 8);
        acc[k] = ((lane & 8) ? acc[k + 4] : acc[k]) + recv;
    }

    float v0 = active ? (acc[0] + __uint_as_float(selfu.x << 16)) * dn : 0.f;
    float v1 = active ? (acc[1] + __uint_as_float(selfu.x & 0xffff0000u)) * dn : 0.f;
    float v2 = active ? (acc[2] + __uint_as_float(selfu.y << 16)) * dn : 0.f;
    float v3 = active ? (acc[3] + __uint_as_float(selfu.y & 0xffff0000u)) * dn : 0.f;

    if (active)
        *(float4*)&out[(size_t)node * C_OUT + c0] = make_float4(v0, v1, v2, v3);

    // fused BN stats: slot = (wave,quarter); unique (slot,channel) writer
    int slot = wv * 4 + q;
    sredS[slot][c0 + 0] = v0;       sredQ[slot][c0 + 0] = v0 * v0;
    sredS[slot][c0 + 1] = v1;       sredQ[slot][c0 + 1] = v1 * v1;
    sredS[slot][c0 + 2] = v2;       sredQ[slot][c0 + 2] = v2 * v2;
    sredS[slot][c0 + 3] = v3;       sredQ[slot][c0 + 3] = v3 * v3;
    __syncthreads();
    int t = threadIdx.x;
    if (t < 128) {
        int cc = t & 63;
        float a = 0.f;
        if (t < 64) {
            #pragma unroll
            for (int j = 0; j < 16; ++j) a += sredS[j][cc];
        } else {
            #pragma unroll
            for (int j = 0; j < 16; ++j) a += sredQ[j][cc];
        }
        atomicAdd(&part[(blockIdx.x & (NPART - 1)) * 128 + t], a);
    }
}

// ---------------------------------------------------------------------------
// K8: BN normalize + LeakyReLU, float4, in-place. Prologue reduces the
// 16x128 stats partials in LDS (8KB, L2-broadcast-hot) -> kills k_stats.
__global__ __launch_bounds__(256) void k_final(const float* __restrict__ part,
                                               const float* __restrict__ gamma,
                                               const float* __restrict__ beta,
                                               float* __restrict__ out, int n) {
    __shared__ float lp[NPART * 128];
    __shared__ float tot[128];
    int t = threadIdx.x;
    #pragma unroll
    for (int r = 0; r < NPART * 128 / 256; ++r)
        lp[t + r * 256] = part[t + r * 256];
    __syncthreads();
    if (t < 128) {
        float a = 0.f;
        #pragma unroll
        for (int j = 0; j < NPART; ++j) a += lp[j * 128 + t];
        tot[t] = a;
    }
    __syncthreads();

    int gid = blockIdx.x * 256 + t;
    int total4 = n * (C_OUT / 4);
    if (gid >= total4) return;
    int c4 = (gid & 15) * 4;
    float inv_n = 1.0f / (float)n;
    float4 g4 = *(const float4*)&gamma[c4];
    float4 b4 = *(const float4*)&beta[c4];
    float4 v = ((const float4*)out)[gid];

    float m, var, k, y;
    m = tot[c4 + 0] * inv_n; var = tot[64 + c4 + 0] * inv_n - m * m;
    k = rsqrtf(var + BN_EPS) * g4.x;
    y = (v.x - m) * k + b4.x; v.x = y >= 0.f ? y : LEAKY * y;
    m = tot[c4 + 1] * inv_n; var = tot[64 + c4 + 1] * inv_n - m * m;
    k = rsqrtf(var + BN_EPS) * g4.y;
    y = (v.y - m) * k + b4.y; v.y = y >= 0.f ? y : LEAKY * y;
    m = tot[c4 + 2] * inv_n; var = tot[64 + c4 + 2] * inv_n - m * m;
    k = rsqrtf(var + BN_EPS) * g4.z;
    y = (v.z - m) * k + b4.z; v.z = y >= 0.f ? y : LEAKY * y;
    m = tot[c4 + 3] * inv_n; var = tot[64 + c4 + 3] * inv_n - m * m;
    k = rsqrtf(var + BN_EPS) * g4.w;
    y = (v.w - m) * k + b4.w; v.w = y >= 0.f ? y : LEAKY * y;

    ((float4*)out)[gid] = v;
}

// ---------------------------------------------------------------------------
extern "C" void kernel_launch(void* const* d_in, const int* in_sizes, int n_in,
                              void* d_out, int out_size, void* d_ws, size_t ws_size,
                              hipStream_t stream) {
    const float* x     = (const float*)d_in[0];
    const int*   ei    = (const int*)d_in[1];
    const float* W     = (const float*)d_in[2];
    // d_in[3] = b: cancels in BatchNorm, unused.
    const float* gamma = (const float*)d_in[4];
    const float* beta  = (const float*)d_in[5];
    float* out = (float*)d_out;

    int n  = in_sizes[0] / C_IN;
    int nE = in_sizes[1] / 2;
    const int* rows = ei;
    const int* cols = ei + nE;
    int NB = (n + BSZ - 1) / BSZ;  // 391 for n=100k (<= NBMAX)

    // ws layout (srcs ALIASES pairs: binB sorts in place):
    // pd[n] int2 | xwsb[n*64] ushort | pairs/srcs[NB*CAP] | bfill[NBMAX] |
    // part[NPART*128] f32 | wb[8192] ushort
    int2* pd = (int2*)d_ws;
    unsigned short* xwsb = (unsigned short*)(pd + n);
    unsigned* pairs = (unsigned*)(xwsb + (size_t)n * C_OUT);
    int* srcs = (int*)pairs;
    int* bfill = (int*)(pairs + (size_t)NB * CAP);
    float* part = (float*)(bfill + NBMAX);
    unsigned short* wb = (unsigned short*)(part + NPART * 128);

    // 6 graph nodes: prep, binA, binB, gemm, gather(+stats), final
    k_prep<<<(C_IN * C_OUT + 255) / 256, 256, 0, stream>>>(W, wb, bfill, part);
    k_binA<<<(nE + CHUNKA - 1) / CHUNKA, 256, 0, stream>>>(rows, cols, bfill, pairs, nE, NB);
    k_binB<<<NB, 256, 0, stream>>>(bfill, pairs, pd, srcs, n);
    k_gemm<<<(n + 63) / 64, 256, 0, stream>>>(x, wb, pd, xwsb, n);
    k_gather<<<(n + 15) / 16, 256, 0, stream>>>(pd, srcs, xwsb, out, part, n);
    k_final<<<(n * (C_OUT / 4) + 255) / 256, 256, 0, stream>>>(part, gamma, beta, out, n);
}